// Round 1
// 278.503 us; speedup vs baseline: 1.0320x; 1.0320x over previous
//
#include <hip/hip_runtime.h>

#define PI_F      3.14159265358979323846f
#define TWO_PI_F  6.28318530717958647692f

typedef float     f4 __attribute__((ext_vector_type(4)));
typedef float     f8 __attribute__((ext_vector_type(8)));
typedef _Float16  h4 __attribute__((ext_vector_type(4)));
typedef _Float16  h8 __attribute__((ext_vector_type(8)));

// Levels: W = 256<<l, H = 64<<l. Only rows rbase..H-1 are ever sampled
// (gy = clip(ts,-1,1) with ts in [0,1] => y >= (H-1)/2), rbase = (32<<l)-1.
// ws layout per level (fp16): texel (r-rbase)*W + x -> 32 contiguous channels.
// Texel counts NT = (H-rbase)*W : {8448, 33280, 132096, 526336} (all %128==0)
// Tile (128 texels) boundaries: 66, 326, 1358, 5470
// Texel bases {0, 8448, 41728, 173824}. Total 22405120 halves = 44.8 MB.

__global__ __launch_bounds__(256) void transpose_half_fp16(
    const float* __restrict__ g0, const float* __restrict__ g1,
    const float* __restrict__ g2, const float* __restrict__ g3,
    _Float16* __restrict__ ws)
{
    // 128 texels x 32 channels staged in LDS; +1 pad keeps aliasing 2-way (free)
    __shared__ float tile_s[128][33];   // 16.9 KB -> 9 blocks/CU LDS-bound

    int b = blockIdx.x;
    int l, tile;
    if (b < 66)        { l = 0; tile = b; }
    else if (b < 326)  { l = 1; tile = b - 66; }
    else if (b < 1358) { l = 2; tile = b - 326; }
    else               { l = 3; tile = b - 1358; }

    const int W     = 256 << l;
    const int HW    = (64 << l) * W;
    const int rbase = (32 << l) - 1;
    const size_t srcOff = (size_t)rbase * W + (size_t)tile * 128;
    const size_t dstTexelBase[4] = {0, 8448, 41728, 173824};
    const float* src = (l == 0) ? g0 : (l == 1) ? g1 : (l == 2) ? g2 : g3;

    const int t = threadIdx.x;
    const int c = t >> 3;     // channel 0..31
    const int q = t & 7;      // quad-in-iteration 0..7

    // load: f32x4 along texel dim; per (block,channel): 4 x 128B = 512B
    // contiguous stream (vs 128B before) -> better DRAM burst efficiency
    const float* srcc = src + (size_t)c * HW + srcOff;
#pragma unroll
    for (int it = 0; it < 4; ++it) {
        const int x = (it * 8 + q) * 4;          // texel base 0..124
        const f4 v = __builtin_nontemporal_load((const f4*)(srcc + x));
        tile_s[x + 0][c] = v.x;
        tile_s[x + 1][c] = v.y;
        tile_s[x + 2][c] = v.z;
        tile_s[x + 3][c] = v.w;
    }
    __syncthreads();

    // store: fp16x4 along channel dim; block writes 8KB contiguous
    const int hw0 = t >> 3;   // texel-in-tile base 0..31
    const int cq  = t & 7;    // channel quad 0..7
    _Float16* dstb = ws + (dstTexelBase[l] + (size_t)tile * 128) * 32 + cq * 4;
#pragma unroll
    for (int it = 0; it < 4; ++it) {
        const int hw = it * 32 + hw0;
        h4 r;
        r.x = (_Float16)tile_s[hw][cq * 4 + 0];
        r.y = (_Float16)tile_s[hw][cq * 4 + 1];
        r.z = (_Float16)tile_s[hw][cq * 4 + 2];
        r.w = (_Float16)tile_s[hw][cq * 4 + 3];
        *(h4*)(dstb + hw * 32) = r;   // cached store: sample pass reuses via L2/LLC
    }
}

// ---------------------------------------------------------------------------
// Sampling from compacted fp16 (row-range, W, C=32) workspace.
// 4 threads per (point, level); each thread owns an 8-channel octet and
// gathers 4 x 16B (dwordx4). Level is blockIdx.y -> wave-uniform shape math.
// ---------------------------------------------------------------------------
__global__ __launch_bounds__(256) void sample_hwc_fp16(
    const float* __restrict__ ts, const float* __restrict__ theta,
    const _Float16* __restrict__ ws, float* __restrict__ out, int BN)
{
    const int l   = blockIdx.y;                 // level 0..3 (wave-uniform)
    const int tid = blockIdx.x * 256 + threadIdx.x;
    const int c8  = tid & 3;                    // channel octet 0..3
    const int p   = tid >> 2;                   // point
    if (p >= BN) return;

    const int Wl    = 256 << l;
    const int Hl    = 64 << l;
    const int rbase = (32 << l) - 1;
    const int Hs    = Hl - rbase;                       // stored rows
    const int base8[4] = {0, 33792, 166912, 695296};    // h8 units (texel*4)

    // --- replicate reference coordinate math exactly (f32) ---
    float th   = theta[p];
    float tt   = (th + PI_F) / TWO_PI_F;
    float wrap = tt - floorf(tt);
    float gx   = 2.0f * wrap - 1.0f;
    float gy   = fminf(fmaxf(ts[p], -1.0f), 1.0f);

    float x = (gx + 1.0f) * 0.5f * (float)(Wl - 1);
    float y = (gy + 1.0f) * 0.5f * (float)(Hl - 1);
    float x0f = floorf(x), y0f = floorf(y);
    float wx = x - x0f,   wy = y - y0f;
    int x0 = min(max((int)x0f, 0), Wl - 1);
    int x1 = min(x0 + 1, Wl - 1);
    int y0 = min(max((int)y0f, 0), Hl - 1);
    int y1 = min(y0 + 1, Hl - 1);

    // rebase rows into the compacted store (clamp for memory safety)
    int yy0 = min(max(y0 - rbase, 0), Hs - 1);
    int yy1 = min(max(y1 - rbase, 0), Hs - 1);

    const h8* wl8 = (const h8*)ws + base8[l];
    const int r0 = yy0 * Wl;
    const int r1 = yy1 * Wl;
    h8 a00 = wl8[(r0 + x0) * 4 + c8];
    h8 a01 = wl8[(r0 + x1) * 4 + c8];
    h8 a10 = wl8[(r1 + x0) * 4 + c8];
    h8 a11 = wl8[(r1 + x1) * 4 + c8];

    float w00 = (1.0f - wx) * (1.0f - wy);
    float w01 = wx * (1.0f - wy);
    float w10 = (1.0f - wx) * wy;
    float w11 = wx * wy;

    f8 r = __builtin_convertvector(a00, f8) * w00
         + __builtin_convertvector(a01, f8) * w01
         + __builtin_convertvector(a10, f8) * w10
         + __builtin_convertvector(a11, f8) * w11;

    // out[p][l*32 + c8*8 .. +7]; output never re-read -> nontemporal
    float* o = out + (size_t)p * 128 + l * 32 + c8 * 8;
    f4 lo = __builtin_shufflevector(r, r, 0, 1, 2, 3);
    f4 hi = __builtin_shufflevector(r, r, 4, 5, 6, 7);
    __builtin_nontemporal_store(lo, (f4*)o);
    __builtin_nontemporal_store(hi, (f4*)o + 1);
}

// ---------------------------------------------------------------------------
// Fallback: sample directly from (C,H,W) f32 grids (used only if ws too small).
// ---------------------------------------------------------------------------
__global__ __launch_bounds__(256) void sample_chw(
    const float* __restrict__ ts, const float* __restrict__ theta,
    const float* __restrict__ g0, const float* __restrict__ g1,
    const float* __restrict__ g2, const float* __restrict__ g3,
    float* __restrict__ out, int BN)
{
    const int tid = blockIdx.x * 256 + threadIdx.x;
    const int c4  = tid & 7;
    const int g   = tid >> 3;
    const int l   = g & 3;
    const int p   = g >> 2;
    if (p >= BN) return;

    const int Wl = 256 << l;
    const int Hl = 64 << l;
    const int HWl = Wl * Hl;
    const float* gl = (l == 0) ? g0 : (l == 1) ? g1 : (l == 2) ? g2 : g3;

    float th   = theta[p];
    float tt   = (th + PI_F) / TWO_PI_F;
    float wrap = tt - floorf(tt);
    float gx   = 2.0f * wrap - 1.0f;
    float gy   = fminf(fmaxf(ts[p], -1.0f), 1.0f);

    float x = (gx + 1.0f) * 0.5f * (float)(Wl - 1);
    float y = (gy + 1.0f) * 0.5f * (float)(Hl - 1);
    float x0f = floorf(x), y0f = floorf(y);
    float wx = x - x0f,   wy = y - y0f;
    int x0 = min(max((int)x0f, 0), Wl - 1);
    int x1 = min(x0 + 1, Wl - 1);
    int y0 = min(max((int)y0f, 0), Hl - 1);
    int y1 = min(y0 + 1, Hl - 1);

    float w00 = (1.0f - wx) * (1.0f - wy);
    float w01 = wx * (1.0f - wy);
    float w10 = (1.0f - wx) * wy;
    float w11 = wx * wy;

    const int r0 = y0 * Wl, r1 = y1 * Wl;
    float res[4];
#pragma unroll
    for (int k = 0; k < 4; ++k) {
        int c = c4 * 4 + k;
        const float* gc = gl + (size_t)c * HWl;
        float a00 = gc[r0 + x0];
        float a01 = gc[r0 + x1];
        float a10 = gc[r1 + x0];
        float a11 = gc[r1 + x1];
        res[k] = a00 * w00 + a01 * w01 + a10 * w10 + a11 * w11;
    }
    f4 r;
    r.x = res[0]; r.y = res[1]; r.z = res[2]; r.w = res[3];
    *((f4*)out + (size_t)p * 32 + l * 8 + c4) = r;
}

extern "C" void kernel_launch(void* const* d_in, const int* in_sizes, int n_in,
                              void* d_out, int out_size, void* d_ws, size_t ws_size,
                              hipStream_t stream)
{
    const float* ts    = (const float*)d_in[0];
    const float* theta = (const float*)d_in[1];
    const float* g[4]  = {(const float*)d_in[2], (const float*)d_in[3],
                          (const float*)d_in[4], (const float*)d_in[5]};
    float* out = (float*)d_out;
    const int BN = in_sizes[0];                  // 4 * 65536 = 262144

    const size_t needBytes = 22405120ull * 2ull; // 42.7 MiB fp16 compacted grids

    if (ws_size >= needBytes) {
        _Float16* ws = (_Float16*)d_ws;
        transpose_half_fp16<<<5470, 256, 0, stream>>>(g[0], g[1], g[2], g[3], ws);
        const int blocksPerLevel = (BN * 4 + 255) / 256;
        dim3 sgrid(blocksPerLevel, 4);
        sample_hwc_fp16<<<sgrid, 256, 0, stream>>>(ts, theta, ws, out, BN);
    } else {
        const int nthreads = BN * 4 * 8;         // 8 threads per (point,level)
        const int nblocks  = (nthreads + 255) / 256;
        sample_chw<<<nblocks, 256, 0, stream>>>(ts, theta, g[0], g[1], g[2], g[3], out, BN);
    }
}